// Round 3
// baseline (511.249 us; speedup 1.0000x reference)
//
#include <hip/hip_runtime.h>
#include <hip/hip_bf16.h>

typedef __attribute__((ext_vector_type(8))) short frag8;
typedef __attribute__((ext_vector_type(4))) float f32x4;

#define ASYNC16(gsrc, ldst) \
  __builtin_amdgcn_global_load_lds((const __attribute__((address_space(1))) void*)(gsrc), \
                                   (__attribute__((address_space(3))) void*)(ldst), 16, 0, 0)

__device__ __forceinline__ float sigmoid_(float x) { return 1.0f / (1.0f + __expf(-x)); }
__device__ __forceinline__ float tanh_(float x)    { return 1.0f - 2.0f / (__expf(2.0f * x) + 1.0f); }

// ---------------- prep: weight conversion / reorder + outO init ----------------
// Wg[n'][k]: n' = (u>>4)*64 + j*16 + (u&15)  (u=unit, j=gate i/f/g/o)
__global__ __launch_bounds__(256) void prep_kernel(
    const float* __restrict__ W_comb, const float* __restrict__ W_ih,
    const float* __restrict__ W_hh, const float* __restrict__ b_ih,
    const float* __restrict__ b_hh, const float* __restrict__ b_out,
    __hip_bfloat16* __restrict__ Wc, __hip_bfloat16* __restrict__ Wg,
    float* __restrict__ biasg, float* __restrict__ outO)
{
  int idx = blockIdx.x * 256 + threadIdx.x;
  const int NW = 2048 * 1024, NC = 512 * 512;
  if (idx < NW) {
    int np = idx >> 10, k = idx & 1023;
    int j = (np >> 4) & 3;
    int u = ((np >> 6) << 4) | (np & 15);
    int n = j * 512 + u;
    float v = (k < 512) ? W_ih[n * 512 + k] : W_hh[n * 512 + (k - 512)];
    Wg[idx] = __float2bfloat16(v);
  } else if (idx < NW + NC) {
    int t = idx - NW;
    int n = t >> 9, k = t & 511;
    Wc[t] = __float2bfloat16(W_comb[n * 513 + 1 + k]);   // skip col 0 (input)
  } else if (idx < NW + NC + 2048) {
    int np = idx - NW - NC;
    int j = (np >> 4) & 3;
    int u = ((np >> 6) << 4) | (np & 15);
    int n = j * 512 + u;
    biasg[np] = b_ih[n] + b_hh[n];
  } else if (idx < NW + NC + 2048 + 16384) {
    outO[idx - NW - NC - 2048] = b_out[0];   // gemv accumulates atomically on top
  }
}

// ---------------- attention: 512 thr, 64 rows/block, 8 rows/wave ----------------
// Wl padded +4 floats per 32 -> ds_read_b128 at lane*8 stride is conflict-free
__global__ __launch_bounds__(512) void attn_kernel(
    const float* __restrict__ inputv, const float* __restrict__ hidden,
    const float* __restrict__ cell, const float* __restrict__ enc,
    const float* __restrict__ W_attn, const float* __restrict__ b_attn,
    __hip_bfloat16* __restrict__ A1, __hip_bfloat16* __restrict__ Z,
    float* __restrict__ outA)
{
  __shared__ float Wl[6 * 1152];   // padded: f(k) = k + (k>>5)*4, k<1024+pad(cell half)
  __shared__ float Wl0[6];
  const int tid = threadIdx.x;
  for (int i = tid; i < 6 * 1024; i += 512) {
    int s = i >> 10, k = i & 1023;
    Wl[s * 1152 + k + ((k >> 5) << 2)] = W_attn[s * 1025 + 1 + k];
  }
  if (tid < 6) Wl0[tid] = W_attn[tid * 1025];
  __syncthreads();
  const int w = tid >> 6, lane = tid & 63;
  const int k8 = lane * 8;
  const int idx0 = k8 + ((k8 >> 5) << 2);      // padded offset for hidden half
  const int idxc = idx0 + 576;                 // padded offset for cell half (k=512+k8)

  for (int rr = 0; rr < 8; ++rr) {
    const long row = (long)blockIdx.x * 64 + w * 8 + rr;
    const float4* hp4 = (const float4*)(hidden + row * 512 + k8);
    const float4* cp4 = (const float4*)(cell + row * 512 + k8);
    float4 h0 = hp4[0], h1 = hp4[1];
    float4 c0 = cp4[0], c1 = cp4[1];

    float acc[6];
#pragma unroll
    for (int s = 0; s < 6; ++s) {
      const float4* wh = (const float4*)(Wl + s * 1152 + idx0);
      const float4* wc = (const float4*)(Wl + s * 1152 + idxc);
      float4 a0 = wh[0], a1 = wh[1], b0 = wc[0], b1 = wc[1];
      acc[s] = h0.x * a0.x + h0.y * a0.y + h0.z * a0.z + h0.w * a0.w
             + h1.x * a1.x + h1.y * a1.y + h1.z * a1.z + h1.w * a1.w
             + c0.x * b0.x + c0.y * b0.y + c0.z * b0.z + c0.w * b0.w
             + c1.x * b1.x + c1.y * b1.y + c1.z * b1.z + c1.w * b1.w;
    }
    float iv = inputv[row];
    float logit[6];
#pragma unroll
    for (int s = 0; s < 6; ++s) {
      float a = acc[s];
#pragma unroll
      for (int d = 32; d > 0; d >>= 1) a += __shfl_xor(a, d);
      logit[s] = a + iv * Wl0[s] + b_attn[s];
    }
    float mx = logit[0];
#pragma unroll
    for (int s = 1; s < 6; ++s) mx = fmaxf(mx, logit[s]);
    float wts[6], tot = 0.f;
#pragma unroll
    for (int s = 0; s < 6; ++s) { wts[s] = __expf(logit[s] - mx); tot += wts[s]; }
    float rt = 1.f / tot;
#pragma unroll
    for (int s = 0; s < 6; ++s) wts[s] *= rt;
    if (lane < 6) {
      float mw = 0.f;
#pragma unroll
      for (int s = 0; s < 6; ++s) if (lane == s) mw = wts[s];
      outA[row * 6 + lane] = mw;
    }
    float a8[8] = {0.f, 0.f, 0.f, 0.f, 0.f, 0.f, 0.f, 0.f};
    const float* ep = enc + row * 3072 + k8;
#pragma unroll
    for (int s = 0; s < 6; ++s) {
      float4 e0 = *(const float4*)(ep + s * 512);
      float4 e1 = *(const float4*)(ep + s * 512 + 4);
      float ws_ = wts[s];
      a8[0] += ws_ * e0.x; a8[1] += ws_ * e0.y; a8[2] += ws_ * e0.z; a8[3] += ws_ * e0.w;
      a8[4] += ws_ * e1.x; a8[5] += ws_ * e1.y; a8[6] += ws_ * e1.z; a8[7] += ws_ * e1.w;
    }
    union { frag8 v; __hip_bfloat16 h[8]; } pa, ph;
    float hv8[8] = {h0.x, h0.y, h0.z, h0.w, h1.x, h1.y, h1.z, h1.w};
#pragma unroll
    for (int i = 0; i < 8; ++i) { pa.h[i] = __float2bfloat16(a8[i]); ph.h[i] = __float2bfloat16(hv8[i]); }
    *(frag8*)(A1 + row * 512 + k8) = pa.v;
    *(frag8*)(Z + row * 1024 + 512 + k8) = ph.v;
  }
}

// ---------------- staging helpers (wave-uniform base + lane*16, HW rule) ----------------
__device__ __forceinline__ void stageB(const __hip_bfloat16* __restrict__ g, int ld,
                                       int row0, int k0, __hip_bfloat16* lds, int tid)
{
  int c0 = tid, c1 = tid + 256;                    // 128x32: row = c>>2, col = (c&3)*8
  const __hip_bfloat16* g0 = g + (long)(row0 + (c0 >> 2)) * ld + k0 + (c0 & 3) * 8;
  const __hip_bfloat16* g1 = g + (long)(row0 + (c1 >> 2)) * ld + k0 + (c1 & 3) * 8;
  char* l0 = (char*)lds + (tid & ~63) * 16;
  ASYNC16(g0, l0);
  ASYNC16(g1, l0 + 4096);
}

__device__ __forceinline__ void stageA256(const __hip_bfloat16* __restrict__ g, int ld,
                                          int row0, int k0, __hip_bfloat16* lds, int tid)
{
  char* l0 = (char*)lds + (tid & ~63) * 16;
#pragma unroll
  for (int t = 0; t < 4; ++t) {
    int c = tid + t * 256;                         // 256x32: row = c>>2, col = (c&3)*8
    const __hip_bfloat16* gp = g + (long)(row0 + (c >> 2)) * ld + k0 + (c & 3) * 8;
    ASYNC16(gp, l0 + t * 4096);
  }
}

// ---------------- comb GEMM: x = relu(A1 @ Wc^T + b + input*w0) ----------------
__global__ __launch_bounds__(256) void comb_gemm(
    const __hip_bfloat16* __restrict__ A, const __hip_bfloat16* __restrict__ Bt,
    const float* __restrict__ b_comb, const float* __restrict__ W_comb,
    const float* __restrict__ inputv, __hip_bfloat16* __restrict__ Z)
{
  __shared__ __align__(16) __hip_bfloat16 As[2][128 * 32];
  __shared__ __align__(16) __hip_bfloat16 Bs[2][128 * 32];
  const int tid = threadIdx.x;
  const int lane = tid & 63, w = tid >> 6;
  const int quad = lane >> 4, l15 = lane & 15;
  const int m0 = blockIdx.x * 128, n0 = blockIdx.y * 128;
  const int wm = (w & 1) * 64, wn = (w >> 1) * 64;

  f32x4 acc[4][4] = {};
  for (int kt = 0; kt < 8; ++kt) {
    int k0 = kt * 64;
    stageB(A, 512, m0, k0, As[0], tid);
    stageB(A, 512, m0, k0 + 32, As[1], tid);
    stageB(Bt, 512, n0, k0, Bs[0], tid);
    stageB(Bt, 512, n0, k0 + 32, Bs[1], tid);
    __syncthreads();
#pragma unroll
    for (int h = 0; h < 2; ++h) {
      frag8 af[4], bf[4];
#pragma unroll
      for (int i = 0; i < 4; ++i)
        af[i] = *(const frag8*)((const short*)As[h] + (wm + i * 16 + l15) * 32 + quad * 8);
#pragma unroll
      for (int j = 0; j < 4; ++j)
        bf[j] = *(const frag8*)((const short*)Bs[h] + (wn + j * 16 + l15) * 32 + quad * 8);
#pragma unroll
      for (int i = 0; i < 4; ++i)
#pragma unroll
        for (int j = 0; j < 4; ++j)
          acc[i][j] = __builtin_amdgcn_mfma_f32_16x16x32_bf16(af[i], bf[j], acc[i][j], 0, 0, 0);
    }
    __syncthreads();
  }
  float bc[4], w0[4];
#pragma unroll
  for (int j = 0; j < 4; ++j) {
    int col = n0 + wn + j * 16 + l15;
    bc[j] = b_comb[col];
    w0[j] = W_comb[col * 513];
  }
#pragma unroll
  for (int i = 0; i < 4; ++i) {
#pragma unroll
    for (int r = 0; r < 4; ++r) {
      int row = m0 + wm + i * 16 + quad * 4 + r;
      float iv = inputv[row];
#pragma unroll
      for (int j = 0; j < 4; ++j) {
        int col = n0 + wn + j * 16 + l15;
        float v = acc[i][j][r] + bc[j] + iv * w0[j];
        Z[(long)row * 1024 + col] = __float2bfloat16(fmaxf(v, 0.0f));
      }
    }
  }
}

// ---------------- gates GEMM (256x128 tile) + LSTM + fused out-gemv ----------------
__global__ __launch_bounds__(256, 2) void gates_gemm(
    const __hip_bfloat16* __restrict__ Zm, const __hip_bfloat16* __restrict__ Wg,
    const float* __restrict__ biasg, const float* __restrict__ cell,
    const float* __restrict__ W_out,
    float* __restrict__ outH, float* __restrict__ outC, float* __restrict__ outO)
{
  __shared__ __align__(16) __hip_bfloat16 As[2][256 * 32];
  __shared__ __align__(16) __hip_bfloat16 Bs[2][128 * 32];
  const int tid = threadIdx.x;
  const int lane = tid & 63, w = tid >> 6;
  const int quad = lane >> 4, l15 = lane & 15;
  const int m0 = blockIdx.x * 256, n0 = blockIdx.y * 128;
  const int wm = (w & 1) * 128, wn = (w >> 1) * 64;

  f32x4 acc[8][4] = {};
  for (int kt = 0; kt < 16; ++kt) {
    int k0 = kt * 64;
    stageA256(Zm, 1024, m0, k0, As[0], tid);
    stageA256(Zm, 1024, m0, k0 + 32, As[1], tid);
    stageB(Wg, 1024, n0, k0, Bs[0], tid);
    stageB(Wg, 1024, n0, k0 + 32, Bs[1], tid);
    __syncthreads();
#pragma unroll
    for (int h = 0; h < 2; ++h) {
      frag8 bf[4];
#pragma unroll
      for (int j = 0; j < 4; ++j)
        bf[j] = *(const frag8*)((const short*)Bs[h] + (wn + j * 16 + l15) * 32 + quad * 8);
#pragma unroll
      for (int i = 0; i < 8; ++i) {
        frag8 af = *(const frag8*)((const short*)As[h] + (wm + i * 16 + l15) * 32 + quad * 8);
#pragma unroll
        for (int j = 0; j < 4; ++j)
          acc[i][j] = __builtin_amdgcn_mfma_f32_16x16x32_bf16(af, bf[j], acc[i][j], 0, 0, 0);
      }
    }
    __syncthreads();
  }
  // register epilogue: lane handles unit u for its 32 rows; fused out-gemv
  const int u = ((n0 + wn) >> 2) + l15;
  const float wout = W_out[u];
  const float bi = biasg[n0 + wn + l15];
  const float bfg = biasg[n0 + wn + 16 + l15];
  const float bgg = biasg[n0 + wn + 32 + l15];
  const float bo = biasg[n0 + wn + 48 + l15];
#pragma unroll
  for (int i = 0; i < 8; ++i) {
#pragma unroll
    for (int r = 0; r < 4; ++r) {
      long row = m0 + wm + i * 16 + quad * 4 + r;
      float cv = cell[row * 512 + u];
      float ig = acc[i][0][r] + bi;
      float fg = acc[i][1][r] + bfg;
      float gg = acc[i][2][r] + bgg;
      float og = acc[i][3][r] + bo;
      float cn = sigmoid_(fg) * cv + sigmoid_(ig) * tanh_(gg);
      float hn = sigmoid_(og) * tanh_(cn);
      outH[row * 512 + u] = hn;
      outC[row * 512 + u] = cn;
      float p = hn * wout;
      p += __shfl_xor(p, 1); p += __shfl_xor(p, 2);
      p += __shfl_xor(p, 4); p += __shfl_xor(p, 8);
      if (l15 == 0) atomicAdd(outO + row, p);
    }
  }
}

extern "C" void kernel_launch(void* const* d_in, const int* in_sizes, int n_in,
                              void* d_out, int out_size, void* d_ws, size_t ws_size,
                              hipStream_t stream) {
  const float* inputv = (const float*)d_in[0];
  const float* hidden = (const float*)d_in[1];
  const float* cell   = (const float*)d_in[2];
  const float* enc    = (const float*)d_in[3];
  const float* W_attn = (const float*)d_in[4];
  const float* b_attn = (const float*)d_in[5];
  const float* W_comb = (const float*)d_in[6];
  const float* b_comb = (const float*)d_in[7];
  const float* W_ih   = (const float*)d_in[8];
  const float* W_hh   = (const float*)d_in[9];
  const float* b_ih   = (const float*)d_in[10];
  const float* b_hh   = (const float*)d_in[11];
  const float* W_out  = (const float*)d_in[12];
  const float* b_out  = (const float*)d_in[13];

  float* out  = (float*)d_out;
  float* outO = out;                       // [16384]
  float* outH = out + 16384;               // [16384,512]
  float* outC = out + 8404992;             // [16384,512]
  float* outA = out + 16793600;            // [16384,1,6]

  char* ws = (char*)d_ws;
  __hip_bfloat16* Z   = (__hip_bfloat16*)ws;                 // [16384,1024] x|hidden bf16
  __hip_bfloat16* A1  = (__hip_bfloat16*)(ws + 33554432);    // [16384,512] attn_applied bf16
  __hip_bfloat16* Wc  = (__hip_bfloat16*)(ws + 50331648);    // [512,512]
  __hip_bfloat16* Wg  = (__hip_bfloat16*)(ws + 50855936);    // [2048,1024]
  float*          bg  = (float*)(ws + 55050240);             // [2048]

  prep_kernel<<<9288, 256, 0, stream>>>(W_comb, W_ih, W_hh, b_ih, b_hh, b_out, Wc, Wg, bg, outO);
  attn_kernel<<<256, 512, 0, stream>>>(inputv, hidden, cell, enc, W_attn, b_attn, A1, Z, outA);
  comb_gemm<<<dim3(128, 4), 256, 0, stream>>>(A1, Wc, b_comb, W_comb, inputv, Z);
  gates_gemm<<<dim3(64, 16), 256, 0, stream>>>(Z, Wg, bg, cell, W_out, outH, outC, outO);
}